// Round 10
// baseline (167.154 us; speedup 1.0000x reference)
//
#include <hip/hip_runtime.h>
#include <math.h>

#define BB 512
#define SS 200
#define DD 512
#define KK 128
#define RR (BB * SS)   // 102400 rows

typedef __attribute__((ext_vector_type(8))) short bf16x8;
typedef __attribute__((ext_vector_type(4))) short bf16x4;
typedef __attribute__((ext_vector_type(4))) float f32x4;

__device__ inline unsigned short f2bf(float f) {
    union { float f; unsigned int u; } v; v.f = f;
    unsigned int r = v.u + 0x7FFFu + ((v.u >> 16) & 1u);   // RNE
    return (unsigned short)(r >> 16);
}

__device__ inline bf16x8 pack8(const float4& a, const float4& b) {
    bf16x8 p;
    p[0] = (short)f2bf(a.x); p[1] = (short)f2bf(a.y);
    p[2] = (short)f2bf(a.z); p[3] = (short)f2bf(a.w);
    p[4] = (short)f2bf(b.x); p[5] = (short)f2bf(b.y);
    p[6] = (short)f2bf(b.z); p[7] = (short)f2bf(b.w);
    return p;
}

__device__ inline float fast_tanh(float x) {
    x = fminf(10.f, fmaxf(-10.f, x));
    float t = exp2f(x * 2.885390081777927f);          // e^(2x)
    return (t - 1.f) * __builtin_amdgcn_rcpf(t + 1.f);
}

// ---------------------------------------------------------------------------
// Wt2 in MFMA-fragment order: chunk t (d=t*32..), col-block n (k=n*16..):
//   Wt2[((t*8+n)*64+l)*8 + j] = bf16(W[d(t,l,j)*KK + k(n,l)])
//   k = n*16 + (l&15),  d = t*32 + (l>>4)*8 + j
// ---------------------------------------------------------------------------
__global__ void wt_kernel(const float* __restrict__ W, unsigned short* __restrict__ Wt2) {
    int i = blockIdx.x * 256 + threadIdx.x;   // over 16*8*64*8 = 65536
    int j = i & 7;
    int l = (i >> 3) & 63;
    int n = (i >> 9) & 7;
    int t = i >> 12;
    int k = n * 16 + (l & 15);
    int d = t * 32 + (l >> 4) * 8 + j;
    Wt2[i] = f2bf(W[d * KK + k]);
}

// ---------------------------------------------------------------------------
// conv: tfh fp32 -> bfA bf16 in A-fragment order.
// i = ((rt*16 + t)*8 + sub)*64 + l ; element j (0..7):
//   row = rt*128 + sub*16 + (l&15),  d = t*32 + (l>>4)*8 + j
// Writes: consecutive threads -> consecutive 16B (perfect). Reads: wave =
// 16 rows x 128B = 16 full lines (L3-resident in steady state).
// ---------------------------------------------------------------------------
__global__ __launch_bounds__(256) void conv_kernel(
    const float* __restrict__ tfh, unsigned short* __restrict__ bfA)
{
    size_t i = (size_t)blockIdx.x * 256 + threadIdx.x;   // 6,553,600
    int l   = (int)(i & 63);
    int sub = (int)((i >> 6) & 7);
    int t   = (int)((i >> 9) & 15);
    size_t rt = i >> 13;
    size_t row = rt * 128 + sub * 16 + (l & 15);
    int d = t * 32 + (l >> 4) * 8;
    const float* s = tfh + row * DD + d;
    float4 v0 = *(const float4*)s;
    float4 v1 = *(const float4*)(s + 4);
    *(bf16x8*)(bfA + i * 8) = pack8(v0, v1);
}

// ---------------------------------------------------------------------------
// frag GEMM: logits[row] = sum_k tanh(A[row,:].W[:,k])*wpk[k] + bias[row%SS]
// A: direct per-lane fragment loads from bfA (bf16, contiguous, no LDS, no cvt).
// B: 8KB/chunk double-buffered in LDS, issue-early regs, 1 barrier/chunk.
// 800 blocks x 256 thr (4 waves, wave w rows w*32..+31), 4 blocks/CU.
// ---------------------------------------------------------------------------
__global__ __launch_bounds__(256, 4) void logits_frag2_kernel(
    const unsigned short* __restrict__ bfA,
    const unsigned short* __restrict__ Wt2,
    const float* __restrict__ wpk,
    const float* __restrict__ bias,
    float* __restrict__ logits)
{
    __shared__ unsigned short Bs[2][4096];   // 8KB per buffer

    int tid = threadIdx.x;
    int w   = tid >> 6;
    int l   = tid & 63;
    int l15 = l & 15;
    int g   = l >> 4;
    int rt  = blockIdx.x;
    int brow = rt * 128;

    // A fragment base: t-stride 4096 shorts, m-stride 512 shorts
    const unsigned short* ap = bfA + ((((size_t)rt * 16) * 8 + w * 2) * 64 + l) * 8;
    // B staging: thread copies 32B: shorts [tid*16, tid*16+16)
    const unsigned short* bsrc = Wt2 + tid * 16;

    f32x4 acc[2][8];
    #pragma unroll
    for (int m = 0; m < 2; ++m)
        #pragma unroll
        for (int n = 0; n < 8; ++n) acc[m][n] = (f32x4){0.f, 0.f, 0.f, 0.f};

    // prologue: stage B chunk 0, load A frags for chunk 0
    {
        bf16x8 s0 = *(const bf16x8*)(bsrc);
        bf16x8 s1 = *(const bf16x8*)(bsrc + 8);
        *(bf16x8*)&Bs[0][tid * 16]     = s0;
        *(bf16x8*)&Bs[0][tid * 16 + 8] = s1;
    }
    bf16x8 a0 = *(const bf16x8*)(ap);
    bf16x8 a1 = *(const bf16x8*)(ap + 512);
    __syncthreads();

    for (int t = 0; t < 16; ++t) {
        int buf = t & 1;
        bf16x8 na0, na1, sb0, sb1;
        if (t < 15) {   // issue next chunk's loads early
            size_t off = (size_t)(t + 1) * 4096;
            na0 = *(const bf16x8*)(ap + off);
            na1 = *(const bf16x8*)(ap + off + 512);
            sb0 = *(const bf16x8*)(bsrc + off);
            sb1 = *(const bf16x8*)(bsrc + off + 8);
        }
        #pragma unroll
        for (int n = 0; n < 8; ++n) {
            bf16x8 bf = *(const bf16x8*)&Bs[buf][n * 512 + l * 8];
            acc[0][n] = __builtin_amdgcn_mfma_f32_16x16x32_bf16(a0, bf, acc[0][n], 0, 0, 0);
            acc[1][n] = __builtin_amdgcn_mfma_f32_16x16x32_bf16(a1, bf, acc[1][n], 0, 0, 0);
        }
        if (t < 15) {
            *(bf16x8*)&Bs[buf ^ 1][tid * 16]     = sb0;
            *(bf16x8*)&Bs[buf ^ 1][tid * 16 + 8] = sb1;
        }
        __syncthreads();
        a0 = na0; a1 = na1;
    }

    // --- epilogue: tanh, weight by wpk, reduce over k within 16-lane group ---
    float wv[8];
    #pragma unroll
    for (int n = 0; n < 8; ++n) wv[n] = wpk[n * 16 + l15];

    float rs[2][4];
    #pragma unroll
    for (int m = 0; m < 2; ++m)
        #pragma unroll
        for (int r = 0; r < 4; ++r) rs[m][r] = 0.f;
    #pragma unroll
    for (int m = 0; m < 2; ++m)
        #pragma unroll
        for (int n = 0; n < 8; ++n)
            #pragma unroll
            for (int r = 0; r < 4; ++r)
                rs[m][r] += fast_tanh(acc[m][n][r]) * wv[n];
    #pragma unroll
    for (int m = 0; m < 2; ++m)
        #pragma unroll
        for (int r = 0; r < 4; ++r) {
            float v = rs[m][r];
            v += __shfl_xor(v, 1, 64);
            v += __shfl_xor(v, 2, 64);
            v += __shfl_xor(v, 4, 64);
            v += __shfl_xor(v, 8, 64);
            rs[m][r] = v;
        }
    if (l15 == 0) {
        #pragma unroll
        for (int m = 0; m < 2; ++m)
            #pragma unroll
            for (int r = 0; r < 4; ++r) {
                int grow = brow + w * 32 + m * 16 + g * 4 + r;
                logits[grow] = rs[m][r] + bias[grow % SS];
            }
    }
}

// ---------------------------------------------------------------------------
// FALLBACK (r8, measured-correct): used only if ws too small for bfA.
// ---------------------------------------------------------------------------
__global__ __launch_bounds__(256, 4) void logits_kernel(
    const float* __restrict__ tfh,
    const unsigned short* __restrict__ Wt2,
    const float* __restrict__ wpk,
    const float* __restrict__ bias,
    float* __restrict__ logits)
{
    __shared__ unsigned short As[128][40];
    int tid = threadIdx.x;
    int w   = tid >> 6;
    int l   = tid & 63;
    int l15 = l & 15;
    int g   = l >> 4;
    int brow = blockIdx.x * 128;
    int r0 = tid >> 3;
    int c4 = tid & 7;
    const float* ap = tfh + (size_t)(brow + r0) * DD + c4 * 4;
    const unsigned short* bp = Wt2 + (size_t)l * 8;

    f32x4 acc[2][8];
    #pragma unroll
    for (int m = 0; m < 2; ++m)
        #pragma unroll
        for (int n = 0; n < 8; ++n) acc[m][n] = (f32x4){0.f, 0.f, 0.f, 0.f};

    for (int t = 0; t < 16; ++t) {
        int d0 = t * 32;
        #pragma unroll
        for (int jj = 0; jj < 4; ++jj) {
            float4 v = *(const float4*)(ap + d0 + (size_t)(32 * jj) * DD);
            bf16x4 p;
            p[0] = (short)f2bf(v.x); p[1] = (short)f2bf(v.y);
            p[2] = (short)f2bf(v.z); p[3] = (short)f2bf(v.w);
            *(bf16x4*)&As[r0 + 32 * jj][c4 * 4] = p;
        }
        __syncthreads();
        bf16x8 af0 = *(const bf16x8*)&As[w * 32 + l15][g * 8];
        bf16x8 af1 = *(const bf16x8*)&As[w * 32 + 16 + l15][g * 8];
        const unsigned short* bt = bp + (size_t)t * (8 * 64 * 8);
        #pragma unroll
        for (int nb = 0; nb < 4; ++nb) {
            bf16x8 b0 = *(const bf16x8*)(bt + (2 * nb) * 512);
            bf16x8 b1 = *(const bf16x8*)(bt + (2 * nb + 1) * 512);
            acc[0][2*nb]   = __builtin_amdgcn_mfma_f32_16x16x32_bf16(af0, b0, acc[0][2*nb],   0, 0, 0);
            acc[1][2*nb]   = __builtin_amdgcn_mfma_f32_16x16x32_bf16(af1, b0, acc[1][2*nb],   0, 0, 0);
            acc[0][2*nb+1] = __builtin_amdgcn_mfma_f32_16x16x32_bf16(af0, b1, acc[0][2*nb+1], 0, 0, 0);
            acc[1][2*nb+1] = __builtin_amdgcn_mfma_f32_16x16x32_bf16(af1, b1, acc[1][2*nb+1], 0, 0, 0);
        }
        __syncthreads();
    }

    float wv[8];
    #pragma unroll
    for (int n = 0; n < 8; ++n) wv[n] = wpk[n * 16 + l15];
    float rs[2][4];
    #pragma unroll
    for (int m = 0; m < 2; ++m)
        #pragma unroll
        for (int r = 0; r < 4; ++r) rs[m][r] = 0.f;
    #pragma unroll
    for (int m = 0; m < 2; ++m)
        #pragma unroll
        for (int n = 0; n < 8; ++n)
            #pragma unroll
            for (int r = 0; r < 4; ++r)
                rs[m][r] += fast_tanh(acc[m][n][r]) * wv[n];
    #pragma unroll
    for (int m = 0; m < 2; ++m)
        #pragma unroll
        for (int r = 0; r < 4; ++r) {
            float v = rs[m][r];
            v += __shfl_xor(v, 1, 64);
            v += __shfl_xor(v, 2, 64);
            v += __shfl_xor(v, 4, 64);
            v += __shfl_xor(v, 8, 64);
            rs[m][r] = v;
        }
    if (l15 == 0) {
        #pragma unroll
        for (int m = 0; m < 2; ++m)
            #pragma unroll
            for (int r = 0; r < 4; ++r) {
                int grow = brow + w * 32 + m * 16 + g * 4 + r;
                logits[grow] = rs[m][r] + bias[grow % SS];
            }
    }
}

// ---------------------------------------------------------------------------
// Pt = softmax(logits[b,:]); out[b,s,:] = Pt[s] * tfh[b,s,:]
// tfh re-read hits L3; non-temporal stores keep tfh resident.
// ---------------------------------------------------------------------------
__global__ __launch_bounds__(1024) void softmax_mul_kernel(
    const float* __restrict__ logits,
    const float* __restrict__ tfh,
    float* __restrict__ out)
{
    int b = blockIdx.x;
    int tid = threadIdx.x;
    __shared__ float Pt[SS];
    __shared__ float wpart[16];

    float v = (tid < SS) ? logits[(size_t)b * SS + tid] : -INFINITY;
    float m = v;
    #pragma unroll
    for (int off = 32; off > 0; off >>= 1) m = fmaxf(m, __shfl_xor(m, off, 64));
    if ((tid & 63) == 0) wpart[tid >> 6] = m;
    __syncthreads();
    m = -INFINITY;
    #pragma unroll
    for (int i = 0; i < 16; ++i) m = fmaxf(m, wpart[i]);
    float e = (tid < SS) ? expf(v - m) : 0.f;
    float ssum = e;
    #pragma unroll
    for (int off = 32; off > 0; off >>= 1) ssum += __shfl_xor(ssum, off, 64);
    __syncthreads();
    if ((tid & 63) == 0) wpart[tid >> 6] = ssum;
    __syncthreads();
    ssum = 0.f;
    #pragma unroll
    for (int i = 0; i < 16; ++i) ssum += wpart[i];
    if (tid < SS) Pt[tid] = e / ssum;
    __syncthreads();

    const f32x4* src = (const f32x4*)(tfh + (size_t)b * SS * DD);
    f32x4*       dst = (f32x4*)(out + (size_t)b * SS * DD);
    const int n4 = SS * DD / 4;   // 25600; 128 f32x4 per s-row
    for (int i = tid; i < n4; i += 1024) {
        float p = Pt[i >> 7];
        f32x4 x = src[i];
        x = x * p;
        __builtin_nontemporal_store(x, dst + i);
    }
}

// ---------------------------------------------------------------------------
extern "C" void kernel_launch(void* const* d_in, const int* in_sizes, int n_in,
                              void* d_out, int out_size, void* d_ws, size_t ws_size,
                              hipStream_t stream) {
    const float* tfh   = (const float*)d_in[1];
    const float* wVt1  = (const float*)d_in[7];
    const float* wp1   = (const float*)d_in[8];
    const float* bias1 = (const float*)d_in[9];
    float* out = (float*)d_out;

    // ws: Wt2 (128KB) @0 | logits (400KB) @128KB | bfA (100MB) @1MB
    unsigned short* Wt2 = (unsigned short*)d_ws;
    float* logits = (float*)((char*)d_ws + (128 << 10));
    unsigned short* bfA = (unsigned short*)((char*)d_ws + (1 << 20));
    const size_t need = (size_t)(1 << 20) + (size_t)RR * DD * 2;

    wt_kernel<<<(16 * 8 * 64 * 8) / 256, 256, 0, stream>>>(wVt1, Wt2);
    if (ws_size >= need) {
        conv_kernel<<<(int)(((size_t)RR * DD / 8) / 256), 256, 0, stream>>>(tfh, bfA);
        logits_frag2_kernel<<<RR / 128, 256, 0, stream>>>(bfA, Wt2, wp1 + KK, bias1, logits);
    } else {
        logits_kernel<<<RR / 128, 256, 0, stream>>>(tfh, Wt2, wp1 + KK, bias1, logits);
    }
    softmax_mul_kernel<<<BB, 1024, 0, stream>>>(logits, tfh, out);
}

// Round 12
// 123.755 us; speedup vs baseline: 1.3507x; 1.3507x over previous
//
#include <hip/hip_runtime.h>
#include <math.h>

#define BB 512
#define SS 200
#define DD 512
#define KK 128
#define RR (BB * SS)   // 102400 rows

typedef __attribute__((ext_vector_type(8))) short bf16x8;
typedef __attribute__((ext_vector_type(4))) short bf16x4;
typedef __attribute__((ext_vector_type(4))) float f32x4;

__device__ inline unsigned short f2bf(float f) {
    union { float f; unsigned int u; } v; v.f = f;
    unsigned int r = v.u + 0x7FFFu + ((v.u >> 16) & 1u);   // RNE
    return (unsigned short)(r >> 16);
}

__device__ inline float fast_tanh(float x) {
    x = fminf(10.f, fmaxf(-10.f, x));
    float t = exp2f(x * 2.885390081777927f);          // e^(2x)
    return (t - 1.f) * __builtin_amdgcn_rcpf(t + 1.f);
}

// ---------------------------------------------------------------------------
// Wt[col][d] = bf16(W[d][col]) — transposed, row-major in d. 128KB, L2-hot.
// ---------------------------------------------------------------------------
__global__ void wt_kernel(const float* __restrict__ W, unsigned short* __restrict__ Wt) {
    int i = blockIdx.x * 256 + threadIdx.x;   // over 128*512
    int col = i >> 9, d = i & 511;
    Wt[i] = f2bf(W[d * KK + col]);
}

// ---------------------------------------------------------------------------
// logits[row] = sum_k tanh(tfh[row,:] . W[:,k]) * wpk[k] + bias[row%SS]
// r2-proven structure, BK=64: A(128x64 f32->bf16) + B(128k x 64d) staged in
// padded LDS each iter; 8 iters x {stage, barrier, 32 MFMA, barrier}.
// 800 blocks x 256 thr (4 waves; wave w owns rows w*32..+31).
// ---------------------------------------------------------------------------
__global__ __launch_bounds__(256, 3) void logits_kernel(
    const float* __restrict__ tfh,           // [RR, DD]
    const unsigned short* __restrict__ Wt,   // [KK][DD] bf16 (transposed W)
    const float* __restrict__ wpk,           // [KK]
    const float* __restrict__ bias,          // [SS]
    float* __restrict__ logits)              // [RR]
{
    __shared__ unsigned short As[128][72];   // 128 rows x 64 d (+8 pad)
    __shared__ unsigned short Bs[128][72];   // 128 k   x 64 d (+8 pad)

    int tid = threadIdx.x;
    int w   = tid >> 6;        // wave 0..3
    int l   = tid & 63;
    int l15 = l & 15;
    int g   = l >> 4;
    int brow = blockIdx.x * 128;

    // A staging map: load j (0..7): row = (tid>>4) + 16*j, float4-col = tid&15
    //   -> 16 consecutive lanes cover one 256B row segment (coalesced)
    int arow = tid >> 4;
    int ac4  = tid & 15;
    const float* ap = tfh + (size_t)(brow + arow) * DD + ac4 * 4;

    // B staging map: load j (0..3): krow = (tid>>3) + 32*j, bf16x8-col = tid&7
    //   -> 8 consecutive lanes cover one 128B k-row segment (coalesced)
    //   4 loads x 256 thr x 8 shorts = 8192 shorts = full 128x64 tile
    int bkrow = tid >> 3;
    int bc8   = tid & 7;
    const unsigned short* bp = Wt + (size_t)bkrow * DD + bc8 * 8;

    f32x4 acc[2][8];
    #pragma unroll
    for (int m = 0; m < 2; ++m)
        #pragma unroll
        for (int n = 0; n < 8; ++n) acc[m][n] = (f32x4){0.f, 0.f, 0.f, 0.f};

    for (int it = 0; it < 8; ++it) {
        int d0 = it * 64;
        // --- stage A: 128 rows x 64 d, fp32 -> bf16 ---
        #pragma unroll
        for (int j = 0; j < 8; ++j) {
            float4 v = *(const float4*)(ap + d0 + (size_t)(16 * j) * DD);
            bf16x4 p;
            p[0] = (short)f2bf(v.x); p[1] = (short)f2bf(v.y);
            p[2] = (short)f2bf(v.z); p[3] = (short)f2bf(v.w);
            *(bf16x4*)&As[arow + 16 * j][ac4 * 4] = p;
        }
        // --- stage B: 128 k x 64 d (already bf16), ALL 128 rows ---
        #pragma unroll
        for (int j = 0; j < 4; ++j) {
            bf16x8 q = *(const bf16x8*)(bp + d0 + (size_t)(32 * j) * DD);
            *(bf16x8*)&Bs[bkrow + 32 * j][bc8 * 8] = q;
        }
        __syncthreads();
        // --- MFMA: two 32-d halves ---
        #pragma unroll
        for (int h = 0; h < 2; ++h) {
            bf16x8 af0 = *(const bf16x8*)&As[w * 32 + l15][h * 32 + g * 8];
            bf16x8 af1 = *(const bf16x8*)&As[w * 32 + 16 + l15][h * 32 + g * 8];
            #pragma unroll
            for (int n = 0; n < 8; ++n) {
                bf16x8 bf = *(const bf16x8*)&Bs[n * 16 + l15][h * 32 + g * 8];
                acc[0][n] = __builtin_amdgcn_mfma_f32_16x16x32_bf16(af0, bf, acc[0][n], 0, 0, 0);
                acc[1][n] = __builtin_amdgcn_mfma_f32_16x16x32_bf16(af1, bf, acc[1][n], 0, 0, 0);
            }
        }
        __syncthreads();
    }

    // --- epilogue: tanh, weight by wpk, reduce over k within 16-lane group ---
    float wv[8];
    #pragma unroll
    for (int n = 0; n < 8; ++n) wv[n] = wpk[n * 16 + l15];

    float rs[2][4];
    #pragma unroll
    for (int m = 0; m < 2; ++m)
        #pragma unroll
        for (int r = 0; r < 4; ++r) rs[m][r] = 0.f;
    #pragma unroll
    for (int m = 0; m < 2; ++m)
        #pragma unroll
        for (int n = 0; n < 8; ++n)
            #pragma unroll
            for (int r = 0; r < 4; ++r)
                rs[m][r] += fast_tanh(acc[m][n][r]) * wv[n];
    #pragma unroll
    for (int m = 0; m < 2; ++m)
        #pragma unroll
        for (int r = 0; r < 4; ++r) {
            float v = rs[m][r];
            v += __shfl_xor(v, 1, 64);
            v += __shfl_xor(v, 2, 64);
            v += __shfl_xor(v, 4, 64);
            v += __shfl_xor(v, 8, 64);
            rs[m][r] = v;
        }
    if (l15 == 0) {
        #pragma unroll
        for (int m = 0; m < 2; ++m)
            #pragma unroll
            for (int r = 0; r < 4; ++r) {
                int grow = brow + w * 32 + m * 16 + g * 4 + r;
                logits[grow] = rs[m][r] + bias[grow % SS];
            }
    }
}

// ---------------------------------------------------------------------------
// Pt = softmax(logits[b,:]); out[b,s,:] = Pt[s] * tfh[b,s,:]
// tfh re-read hits L3; non-temporal stores keep tfh resident.
// ---------------------------------------------------------------------------
__global__ __launch_bounds__(1024) void softmax_mul_kernel(
    const float* __restrict__ logits,
    const float* __restrict__ tfh,
    float* __restrict__ out)
{
    int b = blockIdx.x;
    int tid = threadIdx.x;
    __shared__ float Pt[SS];
    __shared__ float wpart[16];

    float v = (tid < SS) ? logits[(size_t)b * SS + tid] : -INFINITY;
    float m = v;
    #pragma unroll
    for (int off = 32; off > 0; off >>= 1) m = fmaxf(m, __shfl_xor(m, off, 64));
    if ((tid & 63) == 0) wpart[tid >> 6] = m;
    __syncthreads();
    m = -INFINITY;
    #pragma unroll
    for (int i = 0; i < 16; ++i) m = fmaxf(m, wpart[i]);
    float e = (tid < SS) ? expf(v - m) : 0.f;
    float ssum = e;
    #pragma unroll
    for (int off = 32; off > 0; off >>= 1) ssum += __shfl_xor(ssum, off, 64);
    __syncthreads();
    if ((tid & 63) == 0) wpart[tid >> 6] = ssum;
    __syncthreads();
    ssum = 0.f;
    #pragma unroll
    for (int i = 0; i < 16; ++i) ssum += wpart[i];
    if (tid < SS) Pt[tid] = e / ssum;
    __syncthreads();

    const f32x4* src = (const f32x4*)(tfh + (size_t)b * SS * DD);
    f32x4*       dst = (f32x4*)(out + (size_t)b * SS * DD);
    const int n4 = SS * DD / 4;   // 25600; 128 f32x4 per s-row
    for (int i = tid; i < n4; i += 1024) {
        float p = Pt[i >> 7];
        f32x4 x = src[i];
        x = x * p;
        __builtin_nontemporal_store(x, dst + i);
    }
}

// ---------------------------------------------------------------------------
extern "C" void kernel_launch(void* const* d_in, const int* in_sizes, int n_in,
                              void* d_out, int out_size, void* d_ws, size_t ws_size,
                              hipStream_t stream) {
    const float* tfh   = (const float*)d_in[1];
    const float* wVt1  = (const float*)d_in[7];
    const float* wp1   = (const float*)d_in[8];
    const float* bias1 = (const float*)d_in[9];
    float* out = (float*)d_out;

    // ws: Wt bf16 [128][512] (128KB) @0 | logits f32 [RR] (400KB) @128KB
    unsigned short* Wt = (unsigned short*)d_ws;
    float* logits = (float*)((char*)d_ws + (128 << 10));

    wt_kernel<<<KK * DD / 256, 256, 0, stream>>>(wVt1, Wt);
    logits_kernel<<<RR / 128, 256, 0, stream>>>(tfh, Wt, wp1 + KK, bias1, logits);
    softmax_mul_kernel<<<BB, 1024, 0, stream>>>(logits, tfh, out);
}